// Round 2
// baseline (642.077 us; speedup 1.0000x reference)
//
#include <hip/hip_runtime.h>

#define B_TOTAL 131072
#define NF 32
#define NA 8
#define NH 64
#define FG 8                 // f-groups (blocks in f dimension)
#define FPG (NF / FG)        // 4 f's per block
#define ROWS_PER_BLOCK 1024  // rows per block; 256 per wave
#define CHUNKS 4             // 256 rows / 64 rows-per-chunk

using frag_ab = __attribute__((ext_vector_type(8))) short;   // 8 bf16 (4 VGPRs)
using frag_cd = __attribute__((ext_vector_type(4))) float;   // 4 fp32

__device__ __forceinline__ unsigned short f2bf(float x) {
  unsigned u = __float_as_uint(x);
  u = (u + 0x7FFFu + ((u >> 16) & 1u)) >> 16;   // RNE
  return (unsigned short)u;
}

// fa[b][c]: c<32 -> f_t, 32..39 -> a_t, 40 -> 1.0 (bias row), else 0
__global__ void build_fa_kernel(const float* __restrict__ ft, const float* __restrict__ at,
                                unsigned short* __restrict__ fa) {
  int idx = blockIdx.x * 256 + threadIdx.x;   // B*64 total
  int b = idx >> 6, c = idx & 63;
  float v;
  if (c < NF)            v = ft[b * NF + c];
  else if (c < NF + NA)  v = at[b * NA + (c - NF)];
  else if (c == 40)      v = 1.0f;
  else                   v = 0.0f;
  fa[idx] = f2bf(v);
}

// W1 packed to per-lane B-fragment order; row i==40 carries b1 (bias fold)
// idx = (((f*2+ks)*4+nt)*64+lane)*8+j ; value = W1[f][i=ks*32+(l>>4)*8+j][h=nt*16+(l&15)]
__global__ void pack_w1_kernel(const float* __restrict__ W1, const float* __restrict__ b1,
                               unsigned short* __restrict__ w1p) {
  int idx = blockIdx.x * 256 + threadIdx.x;   // 131072 total
  int j = idx & 7, l = (idx >> 3) & 63, nt = (idx >> 9) & 3, ks = (idx >> 11) & 1, f = idx >> 12;
  int g = l >> 4, c = l & 15;
  int i = ks * 32 + g * 8 + j;
  int h = nt * 16 + c;
  float v = 0.0f;
  if (i < NF + NA)            v = W1[(f * (NF + NA) + i) * NH + h];
  else if (i == NF + NA)      v = b1[f * NH + h];
  w1p[idx] = f2bf(v);
}

template <int CTRL>
__device__ __forceinline__ float dpp_xor_add(float v) {   // VALU-pipe butterfly step
  int m = __builtin_amdgcn_update_dpp(0, __float_as_int(v), CTRL, 0xF, 0xF, true);
  return v + __int_as_float(m);
}
template <int PAT>
__device__ __forceinline__ float swz_xor_add(float v) {   // ds_swizzle butterfly step
  int m = __builtin_amdgcn_ds_swizzle(__float_as_int(v), PAT);
  return v + __int_as_float(m);
}

__global__ __launch_bounds__(256, 4) void fused_mlp_kernel(
    const unsigned short* __restrict__ fa, const unsigned short* __restrict__ w1p,
    const float* __restrict__ w2, const float* __restrict__ b2,
    const float* __restrict__ ft, float* __restrict__ out) {
  __shared__ __align__(16) unsigned short wlds[FPG * 4096];  // 32 KB: this block's 4 f weights
  __shared__ __align__(16) float w2l[FPG * NH];              // 1 KB

  const int t = threadIdx.x;
  const int wv = t >> 6;
  const int l = t & 63;
  const int g = l >> 4;
  const int c = l & 15;
  const int fg = blockIdx.x & (FG - 1);   // f-group: 8-way -> maps across XCDs
  const int rcix = blockIdx.x >> 3;       // row-chunk 0..127
  const long row0 = (long)rcix * ROWS_PER_BLOCK + wv * (ROWS_PER_BLOCK / 4);

  // ---- one-time staging: 32 KB of packed W1 + 1 KB W2 for this f-group ----
  {
    const unsigned short* src = w1p + fg * FPG * 4096 + t * 8;
#pragma unroll
    for (int r = 0; r < 8; ++r)
      __builtin_amdgcn_global_load_lds((const __attribute__((address_space(1))) void*)(src + r * 2048),
                                       (__attribute__((address_space(3))) void*)(&wlds[t * 8 + r * 2048]), 16, 0, 0);
    w2l[t] = w2[fg * FPG * NH + t];
  }
  __syncthreads();   // the ONLY barrier in this kernel

  const int rt_own = (l >> 2) & 3;                 // which 16-row tile this lane owns
  const int own_off = rt_own * 16 + g * 4 + (l & 3);  // bijective over 64 lanes
  const float4 b2v = *(const float4*)(b2 + fg * FPG);
  const frag_cd zero4 = {0.f, 0.f, 0.f, 0.f};

  for (int chunk = 0; chunk < CHUNKS; ++chunk) {
    const long rowbase = row0 + chunk * 64;

    // A fragments for 64 rows (held in 32 VGPRs)
    frag_ab afr[4][2];
#pragma unroll
    for (int rt = 0; rt < 4; ++rt)
#pragma unroll
      for (int ks = 0; ks < 2; ++ks)
        afr[rt][ks] = *(const frag_ab*)(fa + (rowbase + rt * 16 + c) * 64 + ks * 32 + g * 8);

    float oacc[FPG];

#pragma unroll
    for (int f = 0; f < FPG; ++f) {
      // B fragments for this f (32 VGPRs, conflict-free ds_read_b128)
      frag_ab bfr[2][4];
#pragma unroll
      for (int ks = 0; ks < 2; ++ks)
#pragma unroll
        for (int nt = 0; nt < 4; ++nt)
          bfr[ks][nt] = *(const frag_ab*)&wlds[(f * 8 + ks * 4 + nt) * 512 + l * 8];

      float w2v[4];
#pragma unroll
      for (int nt = 0; nt < 4; ++nt) w2v[nt] = w2l[f * NH + nt * 16 + c];

#pragma unroll
      for (int rt = 0; rt < 4; ++rt) {
        // layer 1 for this 16-row tile: 8 MFMAs, acc live-range kept short
        frag_cd acc[4];
#pragma unroll
        for (int nt = 0; nt < 4; ++nt) {
          acc[nt] = __builtin_amdgcn_mfma_f32_16x16x32_bf16(afr[rt][0], bfr[0][nt], zero4, 0, 0, 0);
          acc[nt] = __builtin_amdgcn_mfma_f32_16x16x32_bf16(afr[rt][1], bfr[1][nt], acc[nt], 0, 0, 0);
        }
        // layer 2: relu + dot(W2) + 16-lane reduce
        float p[4];
#pragma unroll
        for (int j = 0; j < 4; ++j) {
          float s = fmaxf(acc[0][j], 0.f) * w2v[0];
          s += fmaxf(acc[1][j], 0.f) * w2v[1];
          s += fmaxf(acc[2][j], 0.f) * w2v[2];
          s += fmaxf(acc[3][j], 0.f) * w2v[3];
          s = dpp_xor_add<0xB1>(s);   // lane^1
          s = dpp_xor_add<0x4E>(s);   // lane^2
          p[j] = s;
        }
        float s01 = (l & 1) ? p[1] : p[0];
        float s23 = (l & 1) ? p[3] : p[2];
        float s = (l & 2) ? s23 : s01;   // lane owns value j = l&3
        s = swz_xor_add<0x101F>(s);      // lane^4
        s = swz_xor_add<0x201F>(s);      // lane^8 -> full 16-lane sum
        if (rt == rt_own) oacc[f] = s;   // static predicate after unroll
      }
    }

    // epilogue: lane owns one row; write its 4 f-columns (+b2, +skip)
    const long r = rowbase + own_off;
    const float4 ftv = *(const float4*)(ft + r * NF + fg * FPG);
    float4 o;
    o.x = oacc[0] + b2v.x + ftv.x;
    o.y = oacc[1] + b2v.y + ftv.y;
    o.z = oacc[2] + b2v.z + ftv.z;
    o.w = oacc[3] + b2v.w + ftv.w;
    *(float4*)(out + r * NF + fg * FPG) = o;
  }
}

extern "C" void kernel_launch(void* const* d_in, const int* in_sizes, int n_in,
                              void* d_out, int out_size, void* d_ws, size_t ws_size,
                              hipStream_t stream) {
  const float* ft = (const float*)d_in[0];
  const float* at = (const float*)d_in[1];
  const float* W1 = (const float*)d_in[2];
  const float* b1 = (const float*)d_in[3];
  const float* W2 = (const float*)d_in[4];
  const float* b2 = (const float*)d_in[5];
  float* out = (float*)d_out;

  unsigned short* w1p = (unsigned short*)d_ws;                          // 256 KB
  unsigned short* fa  = (unsigned short*)((char*)d_ws + (1u << 20));    // 16.7 MB @ 1 MB offset

  pack_w1_kernel<<<(NF * 2 * 4 * 64 * 8) / 256, 256, 0, stream>>>(W1, b1, w1p);
  build_fa_kernel<<<(B_TOTAL * 64) / 256, 256, 0, stream>>>(ft, at, fa);
  fused_mlp_kernel<<<(B_TOTAL / ROWS_PER_BLOCK) * FG, 256, 0, stream>>>(fa, w1p, W2, b2, ft, out);
}

// Round 4
// 61.389 us; speedup vs baseline: 10.4591x; 10.4591x over previous
//
#include <hip/hip_runtime.h>

#define B_TOTAL 131072
#define NF 32
#define NA 8
#define NH 64

using frag_ab = __attribute__((ext_vector_type(8))) short;   // 8 bf16 (4 VGPRs)
using frag_cd = __attribute__((ext_vector_type(4))) float;   // 4 fp32
typedef int v2i __attribute__((ext_vector_type(2)));

__device__ __forceinline__ unsigned short f2bf(float x) {
  unsigned u = __float_as_uint(x);
  u = (u + 0x7FFFu + ((u >> 16) & 1u)) >> 16;   // RNE
  return (unsigned short)u;
}

// R1-VERBATIM (hardware-verified): W1 packed per-lane fragments; row i==40 carries b1.
// idx = (((f*2+ks)*4+nt)*64+l)*8+j ; value = W1aug[f][i=ks*32+(l>>4)*8+j][h=nt*16+(l&15)]
__global__ void pack_w1_kernel(const float* __restrict__ W1, const float* __restrict__ b1,
                               unsigned short* __restrict__ w1p) {
  int idx = blockIdx.x * 256 + threadIdx.x;   // 131072 total
  int j = idx & 7, l = (idx >> 3) & 63, nt = (idx >> 9) & 3, ks = (idx >> 11) & 1, f = idx >> 12;
  int g = l >> 4, c = l & 15;
  int i = ks * 32 + g * 8 + j;
  int h = nt * 16 + c;
  float v = 0.0f;
  if (i < NF + NA)            v = W1[(f * (NF + NA) + i) * NH + h];
  else if (i == NF + NA)      v = b1[f * NH + h];
  w1p[idx] = f2bf(v);
}

// w2p[((f*4+g2)*4+rt)*4+j] = W2[f][g2*4 + j + 16*rt]
__global__ void pack_w2_kernel(const float* __restrict__ W2, float* __restrict__ w2p) {
  int idx = blockIdx.x * 256 + threadIdx.x;   // 2048 total
  int j = idx & 3, rt = (idx >> 2) & 3, g2 = (idx >> 4) & 3, f = idx >> 6;
  w2p[idx] = W2[f * NH + g2 * 4 + j + 16 * rt];
}

template <int PAT>
__device__ __forceinline__ float swz_xor_add(float v) {   // verified-in-R2 butterfly step
  int m = __builtin_amdgcn_ds_swizzle(__float_as_int(v), PAT);
  return v + __int_as_float(m);
}

__device__ __forceinline__ float xor32_add(float v) {     // lane^32 exchange on VALU
  v2i p = __builtin_amdgcn_permlane32_swap(__float_as_int(v), __float_as_int(v), false, false);
  return __int_as_float(p.x) + __int_as_float(p.y);
}

__global__ __launch_bounds__(256, 2) void fused_mlp_kernel(
    const float* __restrict__ ft, const float* __restrict__ at,
    const unsigned short* __restrict__ w1p, const float* __restrict__ w2p,
    const float* __restrict__ b2, float* __restrict__ out) {
  __shared__ __align__(16) unsigned short wlds[2][16384];   // dbuf: 4 f's of W1T frags each (2x32KB)

  const int t = threadIdx.x;
  const int wv = t >> 6;
  const int l = t & 63;
  const int g2 = (l >> 4) & 3;   // 16-lane group: k-slice of B / h-quarter of D
  const int c = l & 15;          // column within 16x16 tile
  const long rowb = (long)blockIdx.x * 256 + wv * 64;   // wave owns 64 batch rows

  // ---- stage round 0 (issue first; latency hides under bfr build) ----
  {
    const unsigned short* src = w1p + t * 8;
#pragma unroll
    for (int k = 0; k < 8; ++k)
      __builtin_amdgcn_global_load_lds((const __attribute__((address_space(1))) void*)(src + k * 2048),
                                       (__attribute__((address_space(3))) void*)(&wlds[0][k * 2048 + t * 8]), 16, 0, 0);
  }

  // ---- B-operand fragments (fa^T) in registers: lane l holds col b = rowb+bt*16+c,
  //      k-slice i = ks*32 + g2*8 + j  (i==40 -> bias 1.0) ----
  frag_ab bfr[4][2];
#pragma unroll
  for (int bt = 0; bt < 4; ++bt) {
    const long b = rowb + bt * 16 + c;
    float tmp[8];
    *(float4*)tmp       = *(const float4*)(ft + b * NF + g2 * 8);
    *(float4*)(tmp + 4) = *(const float4*)(ft + b * NF + g2 * 8 + 4);
    frag_ab f0;
#pragma unroll
    for (int j = 0; j < 8; ++j) f0[j] = (short)f2bf(tmp[j]);
    bfr[bt][0] = f0;

    float av[8];
    *(float4*)av       = *(const float4*)(at + b * NA);
    *(float4*)(av + 4) = *(const float4*)(at + b * NA + 4);
    frag_ab f1;
#pragma unroll
    for (int j = 0; j < 8; ++j) {
      unsigned short bias = (j == 0) ? (unsigned short)0x3F80 : (unsigned short)0;
      unsigned short v = (g2 == 0) ? f2bf(av[j]) : ((g2 == 1) ? bias : (unsigned short)0);
      f1[j] = (short)v;
    }
    bfr[bt][1] = f1;
  }

  const frag_cd zero4 = {0.f, 0.f, 0.f, 0.f};
  const float4* w2p4 = (const float4*)w2p;
  const float4* b2v4 = (const float4*)b2;

  for (int r = 0; r < 8; ++r) {
    __syncthreads();   // drains vmcnt: buf[r&1] staged; all waves done reading buf[(r+1)&1]

    if (r < 7) {   // prefetch next round into the just-freed buffer
      const unsigned short* src = w1p + (r + 1) * 16384 + t * 8;
#pragma unroll
      for (int k = 0; k < 8; ++k)
        __builtin_amdgcn_global_load_lds((const __attribute__((address_space(1))) void*)(src + k * 2048),
                                         (__attribute__((address_space(3))) void*)(&wlds[(r + 1) & 1][k * 2048 + t * 8]), 16, 0, 0);
    }

    const unsigned short* buf = wlds[r & 1];
    float res[4];

#pragma unroll
    for (int fo = 0; fo < 4; ++fo) {
      const int f = r * 4 + fo;

      float4 w2v[4];
#pragma unroll
      for (int rt = 0; rt < 4; ++rt) w2v[rt] = w2p4[(f * 4 + g2) * 4 + rt];   // L1 broadcast

      float s[4] = {0.f, 0.f, 0.f, 0.f};
#pragma unroll
      for (int rt = 0; rt < 4; ++rt) {
        // A-operand (W1T): h-tile rt, lane row h = rt*16 + c  (R1-verified layout)
        frag_ab wf0 = *(const frag_ab*)&buf[(((fo * 2 + 0) * 4 + rt) * 64 + l) * 8];
        frag_ab wf1 = *(const frag_ab*)&buf[(((fo * 2 + 1) * 4 + rt) * 64 + l) * 8];
#pragma unroll
        for (int bt = 0; bt < 4; ++bt) {
          frag_cd a = __builtin_amdgcn_mfma_f32_16x16x32_bf16(wf0, bfr[bt][0], zero4, 0, 0, 0);
          a = __builtin_amdgcn_mfma_f32_16x16x32_bf16(wf1, bfr[bt][1], a, 0, 0, 0);
          // D[h,b]: lane holds h = rt*16 + g2*4 + j, b-col = bt*16 + c  -> in-lane layer 2
          s[bt] += fmaxf(a[0], 0.f) * w2v[rt].x;
          s[bt] += fmaxf(a[1], 0.f) * w2v[rt].y;
          s[bt] += fmaxf(a[2], 0.f) * w2v[rt].z;
          s[bt] += fmaxf(a[3], 0.f) * w2v[rt].w;
        }
      }

      // cross-lane: sum the 4 h-quarters (lanes l, l^16, l^32, l^48), per b-tile
      float sb[4];
#pragma unroll
      for (int bt = 0; bt < 4; ++bt) {
        float v = swz_xor_add<0x401F>(s[bt]);   // + lane^16 (DS, R2-verified pattern)
        sb[bt] = xor32_add(v);                  // + lane^32 (VALU permlane)
      }
      // lane owns row rowb + l  ->  bt = g2, col c
      float r01 = (g2 & 1) ? sb[1] : sb[0];
      float r23 = (g2 & 1) ? sb[3] : sb[2];
      res[fo] = (g2 & 2) ? r23 : r01;
    }

    // write this round's 4 output columns for the lane's own row (+b2, +skip)
    const long row = rowb + l;
    float4 bb = b2v4[r];
    float4 fv = *(const float4*)(ft + row * NF + r * 4);
    float4 o;
    o.x = res[0] + bb.x + fv.x;
    o.y = res[1] + bb.y + fv.y;
    o.z = res[2] + bb.z + fv.z;
    o.w = res[3] + bb.w + fv.w;
    *(float4*)(out + row * NF + r * 4) = o;
  }
}

extern "C" void kernel_launch(void* const* d_in, const int* in_sizes, int n_in,
                              void* d_out, int out_size, void* d_ws, size_t ws_size,
                              hipStream_t stream) {
  const float* ft = (const float*)d_in[0];
  const float* at = (const float*)d_in[1];
  const float* W1 = (const float*)d_in[2];
  const float* b1 = (const float*)d_in[3];
  const float* W2 = (const float*)d_in[4];
  const float* b2 = (const float*)d_in[5];
  float* out = (float*)d_out;

  unsigned short* w1p = (unsigned short*)d_ws;                 // 256 KB
  float* w2p = (float*)((char*)d_ws + (1u << 18));             // 8 KB @ 256 KB

  pack_w1_kernel<<<512, 256, 0, stream>>>(W1, b1, w1p);
  pack_w2_kernel<<<8, 256, 0, stream>>>(W2, w2p);
  fused_mlp_kernel<<<B_TOTAL / 256, 256, 0, stream>>>(ft, at, w1p, w2p, b2, out);
}